// Round 1
// baseline (1762.703 us; speedup 1.0000x reference)
//
#include <hip/hip_runtime.h>
#include <hip/hip_bf16.h>
#include <math.h>

#define NTOK 32768
#define DD   1024
#define HH   2048
#define EE   8

#define BM 128
#define BN 128
#define BK 64

typedef __bf16 bf16x8 __attribute__((ext_vector_type(8)));
typedef float  f32x4  __attribute__((ext_vector_type(4)));

__device__ __forceinline__ void gload_lds16(const void* g, void* l) {
  __builtin_amdgcn_global_load_lds((__attribute__((address_space(1))) void*)(g),
                                   (__attribute__((address_space(3))) void*)(l),
                                   16, 0, 0);
}

// ---------------- gating ----------------
__global__ void k_init(int* counts, int* cursor) {
  int i = threadIdx.x;
  if (i < EE) { counts[i] = 0; cursor[i] = 0; }
}

__global__ __launch_bounds__(256) void k_gating(
    const float* __restrict__ x, const float* __restrict__ wg,
    const float* __restrict__ bg, int* __restrict__ eid,
    float* __restrict__ coef, int* __restrict__ counts)
{
  int lane = threadIdx.x & 63;
  int wave = threadIdx.x >> 6;
  int t = blockIdx.x * 4 + wave;
  const float* xr = x + (size_t)t * DD;
  double s[8] = {0,0,0,0,0,0,0,0};
  for (int c = lane; c < DD; c += 64) {
    float xv = xr[c];
    const float* w = wg + c * EE;
#pragma unroll
    for (int e2 = 0; e2 < 8; ++e2) s[e2] += (double)xv * (double)w[e2];
  }
#pragma unroll
  for (int d2 = 1; d2 < 64; d2 <<= 1) {
#pragma unroll
    for (int e2 = 0; e2 < 8; ++e2) s[e2] += __shfl_xor(s[e2], d2, 64);
  }
  if (lane == 0) {
    double m = -1e300; int am = 0;
#pragma unroll
    for (int e2 = 0; e2 < 8; ++e2) {
      double l = s[e2] + (double)bg[e2];
      if (l > m) { m = l; am = e2; }
    }
    double sum = 0.0;
#pragma unroll
    for (int e2 = 0; e2 < 8; ++e2) sum += exp(s[e2] + (double)bg[e2] - m);
    eid[t] = am;
    coef[t] = (float)(1.0 / sum);
    atomicAdd(&counts[am], 1);
  }
}

__global__ void k_scan(const int* __restrict__ counts, int* __restrict__ offs) {
  if (threadIdx.x == 0) {
    int a = 0;
    for (int e = 0; e < EE; ++e) { offs[e] = a; a += counts[e]; }
    offs[EE] = a;
  }
}

__global__ __launch_bounds__(256) void k_bucket(
    const int* __restrict__ eid, const int* __restrict__ offs,
    int* __restrict__ cursor, int* __restrict__ idx)
{
  int t = blockIdx.x * 256 + threadIdx.x;
  int e = eid[t];
  int p = atomicAdd(&cursor[e], 1);
  idx[offs[e] + p] = t;
}

// ---------------- weight transpose+cast: w[e][R][C] f32 -> wt[e][C][R] bf16 --------
__global__ __launch_bounds__(256) void k_transpose(
    const float* __restrict__ w, __bf16* __restrict__ wt, int R, int C)
{
  __shared__ float tile[32][33];
  int e = blockIdx.z;
  int c0 = blockIdx.x * 32, r0 = blockIdx.y * 32;
  const float* we = w + (size_t)e * R * C;
  __bf16* wte = wt + (size_t)e * R * C;
  int tx = threadIdx.x & 31, ty = threadIdx.x >> 5;
#pragma unroll
  for (int j = 0; j < 32; j += 8)
    tile[ty + j][tx] = we[(size_t)(r0 + ty + j) * C + (c0 + tx)];
  __syncthreads();
#pragma unroll
  for (int j = 0; j < 32; j += 8)
    wte[(size_t)(c0 + ty + j) * R + (r0 + tx)] = (__bf16)tile[tx][ty + j];
}

// ---------------- GEMM 1: h = gelu(x_gather @ W1T[e]^T + b1) ----------------
__global__ __launch_bounds__(256) void k_gemm1(
    const float* __restrict__ x, const __bf16* __restrict__ w1t,
    const float* __restrict__ b1, const int* __restrict__ idx,
    const int* __restrict__ offs, __bf16* __restrict__ hbuf)
{
  int mt = blockIdx.x, nt = blockIdx.y, e = blockIdx.z;
  int off = offs[e], cnt = offs[e + 1] - off;
  if (mt * BM >= cnt) return;
  int n0 = nt * BN;

  __shared__ __align__(16) unsigned short sA[BM * BK];
  __shared__ __align__(16) unsigned short sB[BN * BK];
  char* sAc = (char*)sA;
  char* sBc = (char*)sB;

  const int tid = threadIdx.x;
  const int lane = tid & 63;
  const int wid = tid >> 6;
  const int wrow = (wid >> 1) * 64, wcol = (wid & 1) * 64;
  const int lr = lane & 15, lk = lane >> 4;

  // A staging map: 2 threads per row, 32 cols each
  const int ar = tid >> 1;
  const int ah = tid & 1;
  int rla = mt * BM + ar; if (rla >= cnt) rla = cnt - 1;
  const float* asrc = x + (size_t)idx[off + rla] * DD + ah * 32;

  const char* bsrc = (const char*)(w1t + ((size_t)e * HH + n0) * DD);

  f32x4 acc[4][4] = {};

  for (int k0 = 0; k0 < DD; k0 += BK) {
    // B: async global->LDS, pre-swizzled source
#pragma unroll
    for (int i = 0; i < 4; ++i) {
      int q = i * 256 + tid;
      int row = q >> 3;
      int ch = (q & 7) ^ (row & 7);
      gload_lds16(bsrc + (size_t)row * (DD * 2) + (size_t)k0 * 2 + ch * 16,
                  sBc + q * 16);
    }
    // A: f32 load -> bf16 -> swizzled ds_write
    float4 v[8];
#pragma unroll
    for (int i = 0; i < 8; ++i) v[i] = *(const float4*)(asrc + k0 + i * 4);
#pragma unroll
    for (int j = 0; j < 4; ++j) {
      bf16x8 cfr;
      const float* pv = (const float*)&v[j * 2];
#pragma unroll
      for (int u = 0; u < 8; ++u) cfr[u] = (__bf16)pv[u];
      int cb = ah * 4 + j;
      int slot = cb ^ (ar & 7);
      *(bf16x8*)(sAc + ar * 128 + slot * 16) = cfr;
    }
    __syncthreads();

    bf16x8 af[2][4], bfr[2][4];
#pragma unroll
    for (int kk = 0; kk < 2; ++kk) {
#pragma unroll
      for (int m = 0; m < 4; ++m) {
        int row = wrow + m * 16 + lr;
        af[kk][m] = *(const bf16x8*)(sAc + row * 128 + (((kk * 4 + lk) ^ (row & 7)) * 16));
      }
#pragma unroll
      for (int n = 0; n < 4; ++n) {
        int row = wcol + n * 16 + lr;
        bfr[kk][n] = *(const bf16x8*)(sBc + row * 128 + (((kk * 4 + lk) ^ (row & 7)) * 16));
      }
    }
#pragma unroll
    for (int kk = 0; kk < 2; ++kk)
#pragma unroll
      for (int m = 0; m < 4; ++m)
#pragma unroll
        for (int n = 0; n < 4; ++n)
          acc[m][n] = __builtin_amdgcn_mfma_f32_16x16x32_bf16(af[kk][m], bfr[kk][n], acc[m][n], 0, 0, 0);
    __syncthreads();
  }

  // epilogue: bias + exact GELU -> bf16 h (compacted rows)
#pragma unroll
  for (int m = 0; m < 4; ++m) {
    int rbase = mt * BM + wrow + m * 16 + lk * 4;
#pragma unroll
    for (int n = 0; n < 4; ++n) {
      int col = n0 + wcol + n * 16 + lr;
      float bias = b1[e * HH + col];
#pragma unroll
      for (int j2 = 0; j2 < 4; ++j2) {
        int r2 = rbase + j2;
        if (r2 < cnt) {
          float vv = acc[m][n][j2] + bias;
          float g = 0.5f * vv * (1.0f + erff(vv * 0.70710678118654752f));
          hbuf[(size_t)(off + r2) * HH + col] = (__bf16)g;
        }
      }
    }
  }
}

// ---------------- GEMM 2: out = coef * (h @ W2T[e]^T + b2), scattered ----------------
__global__ __launch_bounds__(256) void k_gemm2(
    const __bf16* __restrict__ hbuf, const __bf16* __restrict__ w2t,
    const float* __restrict__ b2, const int* __restrict__ idx,
    const int* __restrict__ offs, const float* __restrict__ coef,
    float* __restrict__ out)
{
  int mt = blockIdx.x, nt = blockIdx.y, e = blockIdx.z;
  int off = offs[e], cnt = offs[e + 1] - off;
  if (mt * BM >= cnt) return;
  int n0 = nt * BN;

  __shared__ __align__(16) unsigned short sA[BM * BK];
  __shared__ __align__(16) unsigned short sB[BN * BK];
  char* sAc = (char*)sA;
  char* sBc = (char*)sB;

  const int tid = threadIdx.x;
  const int lane = tid & 63;
  const int wid = tid >> 6;
  const int wrow = (wid >> 1) * 64, wcol = (wid & 1) * 64;
  const int lr = lane & 15, lk = lane >> 4;

  const char* bsrc = (const char*)(w2t + ((size_t)e * DD + n0) * HH);

  f32x4 acc[4][4] = {};

  for (int k0 = 0; k0 < HH; k0 += BK) {
    // A: compacted h rows, async global->LDS, pre-swizzled
#pragma unroll
    for (int i = 0; i < 4; ++i) {
      int q = i * 256 + tid;
      int row = q >> 3;
      int rl = mt * BM + row; if (rl >= cnt) rl = cnt - 1;
      int ch = (q & 7) ^ (row & 7);
      gload_lds16((const char*)hbuf + ((size_t)(off + rl) * HH + k0) * 2 + ch * 16,
                  sAc + q * 16);
    }
    // B
#pragma unroll
    for (int i = 0; i < 4; ++i) {
      int q = i * 256 + tid;
      int row = q >> 3;
      int ch = (q & 7) ^ (row & 7);
      gload_lds16(bsrc + (size_t)row * (HH * 2) + (size_t)k0 * 2 + ch * 16,
                  sBc + q * 16);
    }
    __syncthreads();

    bf16x8 af[2][4], bfr[2][4];
#pragma unroll
    for (int kk = 0; kk < 2; ++kk) {
#pragma unroll
      for (int m = 0; m < 4; ++m) {
        int row = wrow + m * 16 + lr;
        af[kk][m] = *(const bf16x8*)(sAc + row * 128 + (((kk * 4 + lk) ^ (row & 7)) * 16));
      }
#pragma unroll
      for (int n = 0; n < 4; ++n) {
        int row = wcol + n * 16 + lr;
        bfr[kk][n] = *(const bf16x8*)(sBc + row * 128 + (((kk * 4 + lk) ^ (row & 7)) * 16));
      }
    }
#pragma unroll
    for (int kk = 0; kk < 2; ++kk)
#pragma unroll
      for (int m = 0; m < 4; ++m)
#pragma unroll
        for (int n = 0; n < 4; ++n)
          acc[m][n] = __builtin_amdgcn_mfma_f32_16x16x32_bf16(af[kk][m], bfr[kk][n], acc[m][n], 0, 0, 0);
    __syncthreads();
  }

  // epilogue: scale by coef, add b2, scatter to out rows (f32)
#pragma unroll
  for (int m = 0; m < 4; ++m) {
    int rbase = mt * BM + wrow + m * 16 + lk * 4;
#pragma unroll
    for (int j2 = 0; j2 < 4; ++j2) {
      int r2 = rbase + j2;
      if (r2 < cnt) {
        int t = idx[off + r2];
        float cf = coef[t];
#pragma unroll
        for (int n = 0; n < 4; ++n) {
          int col = n0 + wcol + n * 16 + lr;
          out[(size_t)t * DD + col] = cf * (acc[m][n][j2] + b2[e * DD + col]);
        }
      }
    }
  }
}

// ---------------- launch ----------------
extern "C" void kernel_launch(void* const* d_in, const int* in_sizes, int n_in,
                              void* d_out, int out_size, void* d_ws, size_t ws_size,
                              hipStream_t stream)
{
  const float* x  = (const float*)d_in[0];
  const float* W1 = (const float*)d_in[1];
  const float* b1 = (const float*)d_in[2];
  const float* W2 = (const float*)d_in[3];
  const float* b2 = (const float*)d_in[4];
  const float* Wg = (const float*)d_in[5];
  const float* bg = (const float*)d_in[6];
  float* out = (float*)d_out;

  char* ws = (char*)d_ws;
  size_t o = 0;
  int* counts = (int*)(ws + o); o += 64;
  int* cursor = (int*)(ws + o); o += 64;
  int* offs   = (int*)(ws + o); o += 64;
  int* eid    = (int*)(ws + o); o += (size_t)NTOK * 4;
  float* coef = (float*)(ws + o); o += (size_t)NTOK * 4;
  int* idx    = (int*)(ws + o); o += (size_t)NTOK * 4;
  o = (o + 255) & ~(size_t)255;
  __bf16* w1t = (__bf16*)(ws + o); o += (size_t)EE * HH * DD * 2;
  __bf16* w2t = (__bf16*)(ws + o); o += (size_t)EE * DD * HH * 2;
  __bf16* hbuf = (__bf16*)(ws + o); o += (size_t)NTOK * HH * 2;

  k_init<<<1, 64, 0, stream>>>(counts, cursor);
  k_gating<<<NTOK / 4, 256, 0, stream>>>(x, Wg, bg, eid, coef, counts);
  k_scan<<<1, 1, 0, stream>>>(counts, offs);
  k_bucket<<<NTOK / 256, 256, 0, stream>>>(eid, offs, cursor, idx);
  k_transpose<<<dim3(HH / 32, DD / 32, EE), 256, 0, stream>>>(W1, w1t, DD, HH);
  k_transpose<<<dim3(DD / 32, HH / 32, EE), 256, 0, stream>>>(W2, w2t, HH, DD);
  k_gemm1<<<dim3(NTOK / BM, HH / BN, EE), 256, 0, stream>>>(x, w1t, b1, idx, offs, hbuf);
  k_gemm2<<<dim3(NTOK / BM, DD / BN, EE), 256, 0, stream>>>(hbuf, w2t, b2, idx, offs, coef, out);
}

// Round 2
// 1289.423 us; speedup vs baseline: 1.3670x; 1.3670x over previous
//
#include <hip/hip_runtime.h>
#include <hip/hip_bf16.h>
#include <math.h>

#define NTOK 32768
#define DD   1024
#define HH   2048
#define EE   8

#define BM 128
#define BN 128
#define BK 64
#define MAXT 264   // max M-tiles across experts: 256 + 7 worst-case + pad

typedef __bf16 bf16x8 __attribute__((ext_vector_type(8)));
typedef float  f32x4  __attribute__((ext_vector_type(4)));

__device__ __forceinline__ void gload_lds16(const void* g, void* l) {
  __builtin_amdgcn_global_load_lds((__attribute__((address_space(1))) void*)(g),
                                   (__attribute__((address_space(3))) void*)(l),
                                   16, 0, 0);
}

// ---------------- gating ----------------
__global__ void k_init(int* counts, int* cursor) {
  int i = threadIdx.x;
  if (i < EE) { counts[i] = 0; cursor[i] = 0; }
}

// 1024 blocks x 256 thr; each wave handles 8 tokens serially (f64 dot for
// argmax stability vs the np reference).
__global__ __launch_bounds__(256) void k_gating(
    const float* __restrict__ x, const float* __restrict__ wg,
    const float* __restrict__ bg, int* __restrict__ eid,
    float* __restrict__ coef, int* __restrict__ counts)
{
  int lane = threadIdx.x & 63;
  int wave = threadIdx.x >> 6;
  for (int k = 0; k < 8; ++k) {
    int t = blockIdx.x * 32 + wave * 8 + k;
    const float* xr = x + (size_t)t * DD;
    double s[8] = {0,0,0,0,0,0,0,0};
    for (int c = lane; c < DD; c += 64) {
      float xv = xr[c];
      const float* w = wg + c * EE;
#pragma unroll
      for (int e2 = 0; e2 < 8; ++e2) s[e2] += (double)xv * (double)w[e2];
    }
#pragma unroll
    for (int d2 = 1; d2 < 64; d2 <<= 1) {
#pragma unroll
      for (int e2 = 0; e2 < 8; ++e2) s[e2] += __shfl_xor(s[e2], d2, 64);
    }
    if (lane == 0) {
      double m = -1e300; int am = 0;
#pragma unroll
      for (int e2 = 0; e2 < 8; ++e2) {
        double l = s[e2] + (double)bg[e2];
        if (l > m) { m = l; am = e2; }
      }
      double sum = 0.0;
#pragma unroll
      for (int e2 = 0; e2 < 8; ++e2) sum += exp(s[e2] + (double)bg[e2] - m);
      eid[t] = am;
      coef[t] = (float)(1.0 / sum);
      atomicAdd(&counts[am], 1);
    }
  }
}

// prefix-sum + build tile table (expert, mt) for all M-tiles
__global__ void k_scan(const int* __restrict__ counts, int* __restrict__ offs,
                       int2* __restrict__ tiles) {
  if (threadIdx.x == 0) {
    int a = 0;
    for (int e = 0; e < EE; ++e) { offs[e] = a; a += counts[e]; }
    offs[EE] = a;
    int nt = 0;
    for (int e = 0; e < EE; ++e) {
      int c = counts[e];
      for (int mt = 0; mt * BM < c; ++mt) tiles[nt++] = make_int2(e, mt);
    }
    for (; nt < MAXT; ++nt) tiles[nt] = make_int2(-1, 0);
  }
}

__global__ __launch_bounds__(256) void k_bucket(
    const int* __restrict__ eid, const int* __restrict__ offs,
    int* __restrict__ cursor, int* __restrict__ idx)
{
  int t = blockIdx.x * 256 + threadIdx.x;
  int e = eid[t];
  int p = atomicAdd(&cursor[e], 1);
  idx[offs[e] + p] = t;
}

// ---------------- x -> bf16 (grid-stride) ----------------
__global__ __launch_bounds__(256) void k_xbf(const float* __restrict__ x,
                                             __bf16* __restrict__ xbf) {
  const int n8 = NTOK * DD / 8;
  const int step = gridDim.x * 256;
  for (int i = blockIdx.x * 256 + threadIdx.x; i < n8; i += step) {
    float4 a = *(const float4*)(x + (size_t)i * 8);
    float4 b = *(const float4*)(x + (size_t)i * 8 + 4);
    bf16x8 v;
    v[0] = (__bf16)a.x; v[1] = (__bf16)a.y; v[2] = (__bf16)a.z; v[3] = (__bf16)a.w;
    v[4] = (__bf16)b.x; v[5] = (__bf16)b.y; v[6] = (__bf16)b.z; v[7] = (__bf16)b.w;
    *(bf16x8*)(xbf + (size_t)i * 8) = v;
  }
}

// ---------------- weight transpose+cast: w[e][R][C] f32 -> wt[e][C][R] bf16 --------
// grid (C/32, R/256, E); each block does 8 vertical 32x32 subtiles
__global__ __launch_bounds__(256) void k_transpose(
    const float* __restrict__ w, __bf16* __restrict__ wt, int R, int C)
{
  __shared__ float tile[32][33];
  int e = blockIdx.z;
  int c0 = blockIdx.x * 32, rb = blockIdx.y * 256;
  const float* we = w + (size_t)e * R * C;
  __bf16* wte = wt + (size_t)e * R * C;
  int tx = threadIdx.x & 31, ty = threadIdx.x >> 5;
  for (int s = 0; s < 8; ++s) {
    int r0 = rb + s * 32;
#pragma unroll
    for (int j = 0; j < 32; j += 8)
      tile[ty + j][tx] = we[(size_t)(r0 + ty + j) * C + (c0 + tx)];
    __syncthreads();
#pragma unroll
    for (int j = 0; j < 32; j += 8)
      wte[(size_t)(c0 + ty + j) * R + (r0 + tx)] = (__bf16)tile[tx][ty + j];
    __syncthreads();
  }
}

// ---------------- GEMM 1: h = gelu(xbf_gather @ W1T[e]^T + b1) ----------------
__global__ __launch_bounds__(256) void k_gemm1(
    const __bf16* __restrict__ xbf, const __bf16* __restrict__ w1t,
    const float* __restrict__ b1, const int* __restrict__ idx,
    const int* __restrict__ offs, const int2* __restrict__ tiles,
    __bf16* __restrict__ hbuf)
{
  int2 te = tiles[blockIdx.x];
  int e = te.x;
  if (e < 0) return;
  int mt = te.y, nt = blockIdx.y;
  int off = offs[e], cnt = offs[e + 1] - off;
  int n0 = nt * BN;

  __shared__ __align__(16) unsigned short sA[BM * BK];
  __shared__ __align__(16) unsigned short sB[BN * BK];
  char* sAc = (char*)sA;
  char* sBc = (char*)sB;

  const int tid = threadIdx.x;
  const int lane = tid & 63;
  const int wid = tid >> 6;
  const int wrow = (wid >> 1) * 64, wcol = (wid & 1) * 64;
  const int lr = lane & 15, lk = lane >> 4;

  // per-thread A staging rows (fixed across K): q = i*256+tid, 8 thr/row
  int tokr[4];
#pragma unroll
  for (int i = 0; i < 4; ++i) {
    int row = (i * 256 + tid) >> 3;
    int rl = mt * BM + row; if (rl >= cnt) rl = cnt - 1;
    tokr[i] = idx[off + rl];
  }

  const char* bsrc = (const char*)(w1t + ((size_t)e * HH + n0) * DD);

  f32x4 acc[4][4] = {};

  for (int k0 = 0; k0 < DD; k0 += BK) {
    // A: gathered bf16 rows, async global->LDS, pre-swizzled source
#pragma unroll
    for (int i = 0; i < 4; ++i) {
      int q = i * 256 + tid;
      int row = q >> 3;
      int ch = (q & 7) ^ (row & 7);
      gload_lds16((const char*)xbf + ((size_t)tokr[i] * DD + k0) * 2 + ch * 16,
                  sAc + q * 16);
    }
    // B
#pragma unroll
    for (int i = 0; i < 4; ++i) {
      int q = i * 256 + tid;
      int row = q >> 3;
      int ch = (q & 7) ^ (row & 7);
      gload_lds16(bsrc + (size_t)row * (DD * 2) + (size_t)k0 * 2 + ch * 16,
                  sBc + q * 16);
    }
    __syncthreads();

    bf16x8 af[2][4], bfr[2][4];
#pragma unroll
    for (int kk = 0; kk < 2; ++kk) {
#pragma unroll
      for (int m = 0; m < 4; ++m) {
        int row = wrow + m * 16 + lr;
        af[kk][m] = *(const bf16x8*)(sAc + row * 128 + (((kk * 4 + lk) ^ (row & 7)) * 16));
      }
#pragma unroll
      for (int n = 0; n < 4; ++n) {
        int row = wcol + n * 16 + lr;
        bfr[kk][n] = *(const bf16x8*)(sBc + row * 128 + (((kk * 4 + lk) ^ (row & 7)) * 16));
      }
    }
#pragma unroll
    for (int kk = 0; kk < 2; ++kk)
#pragma unroll
      for (int m = 0; m < 4; ++m)
#pragma unroll
        for (int n = 0; n < 4; ++n)
          acc[m][n] = __builtin_amdgcn_mfma_f32_16x16x32_bf16(af[kk][m], bfr[kk][n], acc[m][n], 0, 0, 0);
    __syncthreads();
  }

  // epilogue: bias + exact GELU -> bf16 h (compacted rows)
#pragma unroll
  for (int m = 0; m < 4; ++m) {
    int rbase = mt * BM + wrow + m * 16 + lk * 4;
#pragma unroll
    for (int n = 0; n < 4; ++n) {
      int col = n0 + wcol + n * 16 + lr;
      float bias = b1[e * HH + col];
#pragma unroll
      for (int j2 = 0; j2 < 4; ++j2) {
        int r2 = rbase + j2;
        if (r2 < cnt) {
          float vv = acc[m][n][j2] + bias;
          float g = 0.5f * vv * (1.0f + erff(vv * 0.70710678118654752f));
          hbuf[(size_t)(off + r2) * HH + col] = (__bf16)g;
        }
      }
    }
  }
}

// ---------------- GEMM 2: out = coef * (h @ W2T[e]^T + b2), scattered ----------------
__global__ __launch_bounds__(256) void k_gemm2(
    const __bf16* __restrict__ hbuf, const __bf16* __restrict__ w2t,
    const float* __restrict__ b2, const int* __restrict__ idx,
    const int* __restrict__ offs, const int2* __restrict__ tiles,
    const float* __restrict__ coef, float* __restrict__ out)
{
  int2 te = tiles[blockIdx.x];
  int e = te.x;
  if (e < 0) return;
  int mt = te.y, nt = blockIdx.y;
  int off = offs[e], cnt = offs[e + 1] - off;
  int n0 = nt * BN;

  __shared__ __align__(16) unsigned short sA[BM * BK];
  __shared__ __align__(16) unsigned short sB[BN * BK];
  char* sAc = (char*)sA;
  char* sBc = (char*)sB;

  const int tid = threadIdx.x;
  const int lane = tid & 63;
  const int wid = tid >> 6;
  const int wrow = (wid >> 1) * 64, wcol = (wid & 1) * 64;
  const int lr = lane & 15, lk = lane >> 4;

  // compacted A rows (clamped)
  int arow[4];
#pragma unroll
  for (int i = 0; i < 4; ++i) {
    int row = (i * 256 + tid) >> 3;
    int rl = mt * BM + row; if (rl >= cnt) rl = cnt - 1;
    arow[i] = off + rl;
  }

  const char* bsrc = (const char*)(w2t + ((size_t)e * DD + n0) * HH);

  f32x4 acc[4][4] = {};

  for (int k0 = 0; k0 < HH; k0 += BK) {
#pragma unroll
    for (int i = 0; i < 4; ++i) {
      int q = i * 256 + tid;
      int ch = (q & 7) ^ ((q >> 3) & 7);
      gload_lds16((const char*)hbuf + ((size_t)arow[i] * HH + k0) * 2 + ch * 16,
                  sAc + q * 16);
    }
#pragma unroll
    for (int i = 0; i < 4; ++i) {
      int q = i * 256 + tid;
      int row = q >> 3;
      int ch = (q & 7) ^ (row & 7);
      gload_lds16(bsrc + (size_t)row * (HH * 2) + (size_t)k0 * 2 + ch * 16,
                  sBc + q * 16);
    }
    __syncthreads();

    bf16x8 af[2][4], bfr[2][4];
#pragma unroll
    for (int kk = 0; kk < 2; ++kk) {
#pragma unroll
      for (int m = 0; m < 4; ++m) {
        int row = wrow + m * 16 + lr;
        af[kk][m] = *(const bf16x8*)(sAc + row * 128 + (((kk * 4 + lk) ^ (row & 7)) * 16));
      }
#pragma unroll
      for (int n = 0; n < 4; ++n) {
        int row = wcol + n * 16 + lr;
        bfr[kk][n] = *(const bf16x8*)(sBc + row * 128 + (((kk * 4 + lk) ^ (row & 7)) * 16));
      }
    }
#pragma unroll
    for (int kk = 0; kk < 2; ++kk)
#pragma unroll
      for (int m = 0; m < 4; ++m)
#pragma unroll
        for (int n = 0; n < 4; ++n)
          acc[m][n] = __builtin_amdgcn_mfma_f32_16x16x32_bf16(af[kk][m], bfr[kk][n], acc[m][n], 0, 0, 0);
    __syncthreads();
  }

  // epilogue: scale by coef, add b2, scatter to out rows (f32)
#pragma unroll
  for (int m = 0; m < 4; ++m) {
    int rbase = mt * BM + wrow + m * 16 + lk * 4;
#pragma unroll
    for (int j2 = 0; j2 < 4; ++j2) {
      int r2 = rbase + j2;
      if (r2 < cnt) {
        int t = idx[off + r2];
        float cf = coef[t];
#pragma unroll
        for (int n = 0; n < 4; ++n) {
          int col = n0 + wcol + n * 16 + lr;
          out[(size_t)t * DD + col] = cf * (acc[m][n][j2] + b2[e * DD + col]);
        }
      }
    }
  }
}

// ---------------- launch ----------------
extern "C" void kernel_launch(void* const* d_in, const int* in_sizes, int n_in,
                              void* d_out, int out_size, void* d_ws, size_t ws_size,
                              hipStream_t stream)
{
  const float* x  = (const float*)d_in[0];
  const float* W1 = (const float*)d_in[1];
  const float* b1 = (const float*)d_in[2];
  const float* W2 = (const float*)d_in[3];
  const float* b2 = (const float*)d_in[4];
  const float* Wg = (const float*)d_in[5];
  const float* bg = (const float*)d_in[6];
  float* out = (float*)d_out;

  char* ws = (char*)d_ws;
  size_t o = 0;
  int* counts = (int*)(ws + o); o += 64;
  int* cursor = (int*)(ws + o); o += 64;
  int* offs   = (int*)(ws + o); o += 64;
  int2* tiles = (int2*)(ws + o); o += MAXT * 8;
  int* eid    = (int*)(ws + o); o += (size_t)NTOK * 4;
  float* coef = (float*)(ws + o); o += (size_t)NTOK * 4;
  int* idx    = (int*)(ws + o); o += (size_t)NTOK * 4;
  o = (o + 255) & ~(size_t)255;
  __bf16* xbf = (__bf16*)(ws + o); o += (size_t)NTOK * DD * 2;
  __bf16* w1t = (__bf16*)(ws + o); o += (size_t)EE * HH * DD * 2;
  __bf16* w2t = (__bf16*)(ws + o); o += (size_t)EE * DD * HH * 2;
  __bf16* hbuf = (__bf16*)(ws + o); o += (size_t)NTOK * HH * 2;

  k_init<<<1, 64, 0, stream>>>(counts, cursor);
  k_gating<<<NTOK / 32, 256, 0, stream>>>(x, Wg, bg, eid, coef, counts);
  k_scan<<<1, 1, 0, stream>>>(counts, offs, tiles);
  k_bucket<<<NTOK / 256, 256, 0, stream>>>(eid, offs, cursor, idx);
  k_xbf<<<2048, 256, 0, stream>>>(x, xbf);
  k_transpose<<<dim3(HH / 32, DD / 256, EE), 256, 0, stream>>>(W1, w1t, DD, HH);
  k_transpose<<<dim3(DD / 32, HH / 256, EE), 256, 0, stream>>>(W2, w2t, HH, DD);
  k_gemm1<<<dim3(MAXT, HH / BN), 256, 0, stream>>>(xbf, w1t, b1, idx, offs, tiles, hbuf);
  k_gemm2<<<dim3(MAXT, DD / BN), 256, 0, stream>>>(hbuf, w2t, b2, idx, offs, tiles, coef, out);
}

// Round 3
// 883.700 us; speedup vs baseline: 1.9947x; 1.4591x over previous
//
#include <hip/hip_runtime.h>
#include <hip/hip_bf16.h>
#include <math.h>

#define NTOK 32768
#define DD   1024
#define HH   2048
#define EE   8

#define BM 128
#define BN 128
#define BK 64
#define MAXT 264   // max M-tiles across experts: 256 + 7 worst-case + pad
#define NBLK 128   // NTOK / 256

typedef __bf16 bf16x8 __attribute__((ext_vector_type(8)));
typedef float  f32x4  __attribute__((ext_vector_type(4)));

__device__ __forceinline__ void gload_lds16(const void* g, void* l) {
  __builtin_amdgcn_global_load_lds((__attribute__((address_space(1))) void*)(g),
                                   (__attribute__((address_space(3))) void*)(l),
                                   16, 0, 0);
}

// ---------------- gating: eid + coef only, no atomics ----------------
// grid 4096 x 256 thr; each wave handles 2 tokens (shared Wg reads).
// f64 accumulation so our argmax matches the "true" result (np f32 ref
// is ~2e-5 off true; f64 keeps us on the right side of near-ties).
__global__ __launch_bounds__(256) void k_gating(
    const float* __restrict__ x, const float* __restrict__ wg,
    const float* __restrict__ bg, int* __restrict__ eid,
    float* __restrict__ coef)
{
  int lane = threadIdx.x & 63;
  int wave = threadIdx.x >> 6;
  int t0 = blockIdx.x * 8 + wave * 2;

  const float* xr0 = x + (size_t)t0 * DD;
  const float* xr1 = x + (size_t)(t0 + 1) * DD;
  double s0[8] = {}, s1[8] = {};
#pragma unroll
  for (int it = 0; it < 4; ++it) {
    int c0 = it * 256 + lane * 4;
    float4 xa = *(const float4*)(xr0 + c0);
    float4 xb = *(const float4*)(xr1 + c0);
    const float* w = wg + (size_t)c0 * EE;
#pragma unroll
    for (int j = 0; j < 4; ++j) {
      double fa = (double)(&xa.x)[j];
      double fb = (double)(&xb.x)[j];
#pragma unroll
      for (int e2 = 0; e2 < 8; ++e2) {
        double wv = (double)w[j * EE + e2];
        s0[e2] += fa * wv;
        s1[e2] += fb * wv;
      }
    }
  }

  int sel = lane & 1, sel2 = (lane >> 1) & 1, sel3 = (lane >> 2) & 1;
  int e = (lane & 1) * 4 + (lane & 2) + ((lane >> 2) & 1);
  double bge = (double)bg[e];

#pragma unroll
  for (int tk = 0; tk < 2; ++tk) {
    double* s = tk ? s1 : s0;
    // fold 8 experts across lanes: exchange discarded half each step
    double v4[4];
#pragma unroll
    for (int j = 0; j < 4; ++j) {
      double keep = sel ? s[4 + j] : s[j];
      double send = sel ? s[j] : s[4 + j];
      v4[j] = keep + __shfl_xor(send, 1, 64);
    }
    double v2[2];
#pragma unroll
    for (int j = 0; j < 2; ++j) {
      double keep = sel2 ? v4[2 + j] : v4[j];
      double send = sel2 ? v4[j] : v4[2 + j];
      v2[j] = keep + __shfl_xor(send, 2, 64);
    }
    double keep = sel3 ? v2[1] : v2[0];
    double send = sel3 ? v2[0] : v2[1];
    double tt = keep + __shfl_xor(send, 4, 64);
    tt += __shfl_xor(tt, 8, 64);
    tt += __shfl_xor(tt, 16, 64);
    tt += __shfl_xor(tt, 32, 64);
    double logit = tt + bge;
    // argmax over the 8 lanes of each group (tie -> smaller e, np semantics)
    double ml = logit; int me = e;
#pragma unroll
    for (int d2 = 1; d2 < 8; d2 <<= 1) {
      double ol = __shfl_xor(ml, d2, 64);
      int oe = __shfl_xor(me, d2, 64);
      if (ol > ml || (ol == ml && oe < me)) { ml = ol; me = oe; }
    }
    double se = exp(logit - ml);
#pragma unroll
    for (int d2 = 1; d2 < 8; d2 <<= 1) se += __shfl_xor(se, d2, 64);
    if (lane == 0) {
      eid[t0 + tk] = me;
      coef[t0 + tk] = (float)(1.0 / se);
    }
  }
}

// ---------------- per-block histogram (LDS atomics only) ----------------
__global__ __launch_bounds__(256) void k_hist(const int* __restrict__ eid,
                                              int* __restrict__ bhist) {
  __shared__ int h[EE];
  if (threadIdx.x < EE) h[threadIdx.x] = 0;
  __syncthreads();
  int t = blockIdx.x * 256 + threadIdx.x;
  atomicAdd(&h[eid[t]], 1);
  __syncthreads();
  if (threadIdx.x < EE) bhist[blockIdx.x * EE + threadIdx.x] = h[threadIdx.x];
}

// ---------------- scan: offs, per-block bases, tile table ----------------
__global__ void k_scan(const int* __restrict__ bhist, int* __restrict__ offs,
                       int* __restrict__ bbase, int2* __restrict__ tiles) {
  __shared__ int counts_s[EE];
  __shared__ int offs_s[EE + 1];
  int lane = threadIdx.x;
  if (lane < EE) {
    int sum = 0;
    for (int b = 0; b < NBLK; ++b) sum += bhist[b * EE + lane];
    counts_s[lane] = sum;
  }
  __syncthreads();
  if (lane == 0) {
    int a = 0;
    for (int e = 0; e < EE; ++e) { offs_s[e] = a; offs[e] = a; a += counts_s[e]; }
    offs_s[EE] = a; offs[EE] = a;
    int nt = 0;
    for (int e = 0; e < EE; ++e)
      for (int mt = 0; mt * BM < counts_s[e]; ++mt) tiles[nt++] = make_int2(e, mt);
    for (; nt < MAXT; ++nt) tiles[nt] = make_int2(-1, 0);
  }
  __syncthreads();
  if (lane < EE) {
    int run = offs_s[lane];
    for (int b = 0; b < NBLK; ++b) {
      bbase[b * EE + lane] = run;
      run += bhist[b * EE + lane];
    }
  }
}

// ---------------- scatter via LDS cursors into disjoint ranges ----------------
__global__ __launch_bounds__(256) void k_scatter(const int* __restrict__ eid,
                                                 const int* __restrict__ bbase,
                                                 int* __restrict__ idx) {
  __shared__ int cur[EE];
  if (threadIdx.x < EE) cur[threadIdx.x] = bbase[blockIdx.x * EE + threadIdx.x];
  __syncthreads();
  int t = blockIdx.x * 256 + threadIdx.x;
  int e = eid[t];
  int p = atomicAdd(&cur[e], 1);
  idx[p] = t;
}

// ---------------- x -> bf16 (grid-stride) ----------------
__global__ __launch_bounds__(256) void k_xbf(const float* __restrict__ x,
                                             __bf16* __restrict__ xbf) {
  const int n8 = NTOK * DD / 8;
  const int step = gridDim.x * 256;
  for (int i = blockIdx.x * 256 + threadIdx.x; i < n8; i += step) {
    float4 a = *(const float4*)(x + (size_t)i * 8);
    float4 b = *(const float4*)(x + (size_t)i * 8 + 4);
    bf16x8 v;
    v[0] = (__bf16)a.x; v[1] = (__bf16)a.y; v[2] = (__bf16)a.z; v[3] = (__bf16)a.w;
    v[4] = (__bf16)b.x; v[5] = (__bf16)b.y; v[6] = (__bf16)b.z; v[7] = (__bf16)b.w;
    *(bf16x8*)(xbf + (size_t)i * 8) = v;
  }
}

// ---------------- weight transpose+cast: w[e][R][C] f32 -> wt[e][C][R] bf16 --------
__global__ __launch_bounds__(256) void k_transpose(
    const float* __restrict__ w, __bf16* __restrict__ wt, int R, int C)
{
  __shared__ float tile[32][33];
  int e = blockIdx.z;
  int c0 = blockIdx.x * 32, rb = blockIdx.y * 256;
  const float* we = w + (size_t)e * R * C;
  __bf16* wte = wt + (size_t)e * R * C;
  int tx = threadIdx.x & 31, ty = threadIdx.x >> 5;
  for (int s = 0; s < 8; ++s) {
    int r0 = rb + s * 32;
#pragma unroll
    for (int j = 0; j < 32; j += 8)
      tile[ty + j][tx] = we[(size_t)(r0 + ty + j) * C + (c0 + tx)];
    __syncthreads();
#pragma unroll
    for (int j = 0; j < 32; j += 8)
      wte[(size_t)(c0 + ty + j) * R + (r0 + tx)] = (__bf16)tile[tx][ty + j];
    __syncthreads();
  }
}

// ---------------- GEMM 1: h = gelu(xbf_gather @ W1T[e]^T + b1) ----------------
__global__ __launch_bounds__(256) void k_gemm1(
    const __bf16* __restrict__ xbf, const __bf16* __restrict__ w1t,
    const float* __restrict__ b1, const int* __restrict__ idx,
    const int* __restrict__ offs, const int2* __restrict__ tiles,
    __bf16* __restrict__ hbuf)
{
  int2 te = tiles[blockIdx.x];
  int e = te.x;
  if (e < 0) return;
  int mt = te.y, nt = blockIdx.y;
  int off = offs[e], cnt = offs[e + 1] - off;
  int n0 = nt * BN;

  __shared__ __align__(16) unsigned short sA[BM * BK];
  __shared__ __align__(16) unsigned short sB[BN * BK];
  char* sAc = (char*)sA;
  char* sBc = (char*)sB;

  const int tid = threadIdx.x;
  const int lane = tid & 63;
  const int wid = tid >> 6;
  const int wrow = (wid >> 1) * 64, wcol = (wid & 1) * 64;
  const int lr = lane & 15, lk = lane >> 4;

  int tokr[4];
#pragma unroll
  for (int i = 0; i < 4; ++i) {
    int row = (i * 256 + tid) >> 3;
    int rl = mt * BM + row; if (rl >= cnt) rl = cnt - 1;
    tokr[i] = idx[off + rl];
  }

  const char* bsrc = (const char*)(w1t + ((size_t)e * HH + n0) * DD);

  f32x4 acc[4][4] = {};

  for (int k0 = 0; k0 < DD; k0 += BK) {
#pragma unroll
    for (int i = 0; i < 4; ++i) {
      int q = i * 256 + tid;
      int row = q >> 3;
      int ch = (q & 7) ^ (row & 7);
      gload_lds16((const char*)xbf + ((size_t)tokr[i] * DD + k0) * 2 + ch * 16,
                  sAc + q * 16);
    }
#pragma unroll
    for (int i = 0; i < 4; ++i) {
      int q = i * 256 + tid;
      int row = q >> 3;
      int ch = (q & 7) ^ (row & 7);
      gload_lds16(bsrc + (size_t)row * (DD * 2) + (size_t)k0 * 2 + ch * 16,
                  sBc + q * 16);
    }
    __syncthreads();

    bf16x8 af[2][4], bfr[2][4];
#pragma unroll
    for (int kk = 0; kk < 2; ++kk) {
#pragma unroll
      for (int m = 0; m < 4; ++m) {
        int row = wrow + m * 16 + lr;
        af[kk][m] = *(const bf16x8*)(sAc + row * 128 + (((kk * 4 + lk) ^ (row & 7)) * 16));
      }
#pragma unroll
      for (int n = 0; n < 4; ++n) {
        int row = wcol + n * 16 + lr;
        bfr[kk][n] = *(const bf16x8*)(sBc + row * 128 + (((kk * 4 + lk) ^ (row & 7)) * 16));
      }
    }
#pragma unroll
    for (int kk = 0; kk < 2; ++kk)
#pragma unroll
      for (int m = 0; m < 4; ++m)
#pragma unroll
        for (int n = 0; n < 4; ++n)
          acc[m][n] = __builtin_amdgcn_mfma_f32_16x16x32_bf16(af[kk][m], bfr[kk][n], acc[m][n], 0, 0, 0);
    __syncthreads();
  }

#pragma unroll
  for (int m = 0; m < 4; ++m) {
    int rbase = mt * BM + wrow + m * 16 + lk * 4;
#pragma unroll
    for (int n = 0; n < 4; ++n) {
      int col = n0 + wcol + n * 16 + lr;
      float bias = b1[e * HH + col];
#pragma unroll
      for (int j2 = 0; j2 < 4; ++j2) {
        int r2 = rbase + j2;
        if (r2 < cnt) {
          float vv = acc[m][n][j2] + bias;
          float g = 0.5f * vv * (1.0f + erff(vv * 0.70710678118654752f));
          hbuf[(size_t)(off + r2) * HH + col] = (__bf16)g;
        }
      }
    }
  }
}

// ---------------- GEMM 2: out = coef * (h @ W2T[e]^T + b2), scattered ----------------
__global__ __launch_bounds__(256) void k_gemm2(
    const __bf16* __restrict__ hbuf, const __bf16* __restrict__ w2t,
    const float* __restrict__ b2, const int* __restrict__ idx,
    const int* __restrict__ offs, const int2* __restrict__ tiles,
    const float* __restrict__ coef, float* __restrict__ out)
{
  int2 te = tiles[blockIdx.x];
  int e = te.x;
  if (e < 0) return;
  int mt = te.y, nt = blockIdx.y;
  int off = offs[e], cnt = offs[e + 1] - off;
  int n0 = nt * BN;

  __shared__ __align__(16) unsigned short sA[BM * BK];
  __shared__ __align__(16) unsigned short sB[BN * BK];
  char* sAc = (char*)sA;
  char* sBc = (char*)sB;

  const int tid = threadIdx.x;
  const int lane = tid & 63;
  const int wid = tid >> 6;
  const int wrow = (wid >> 1) * 64, wcol = (wid & 1) * 64;
  const int lr = lane & 15, lk = lane >> 4;

  int arow[4];
#pragma unroll
  for (int i = 0; i < 4; ++i) {
    int row = (i * 256 + tid) >> 3;
    int rl = mt * BM + row; if (rl >= cnt) rl = cnt - 1;
    arow[i] = off + rl;
  }

  const char* bsrc = (const char*)(w2t + ((size_t)e * DD + n0) * HH);

  f32x4 acc[4][4] = {};

  for (int k0 = 0; k0 < HH; k0 += BK) {
#pragma unroll
    for (int i = 0; i < 4; ++i) {
      int q = i * 256 + tid;
      int ch = (q & 7) ^ ((q >> 3) & 7);
      gload_lds16((const char*)hbuf + ((size_t)arow[i] * HH + k0) * 2 + ch * 16,
                  sAc + q * 16);
    }
#pragma unroll
    for (int i = 0; i < 4; ++i) {
      int q = i * 256 + tid;
      int row = q >> 3;
      int ch = (q & 7) ^ (row & 7);
      gload_lds16(bsrc + (size_t)row * (HH * 2) + (size_t)k0 * 2 + ch * 16,
                  sBc + q * 16);
    }
    __syncthreads();

    bf16x8 af[2][4], bfr[2][4];
#pragma unroll
    for (int kk = 0; kk < 2; ++kk) {
#pragma unroll
      for (int m = 0; m < 4; ++m) {
        int row = wrow + m * 16 + lr;
        af[kk][m] = *(const bf16x8*)(sAc + row * 128 + (((kk * 4 + lk) ^ (row & 7)) * 16));
      }
#pragma unroll
      for (int n = 0; n < 4; ++n) {
        int row = wcol + n * 16 + lr;
        bfr[kk][n] = *(const bf16x8*)(sBc + row * 128 + (((kk * 4 + lk) ^ (row & 7)) * 16));
      }
    }
#pragma unroll
    for (int kk = 0; kk < 2; ++kk)
#pragma unroll
      for (int m = 0; m < 4; ++m)
#pragma unroll
        for (int n = 0; n < 4; ++n)
          acc[m][n] = __builtin_amdgcn_mfma_f32_16x16x32_bf16(af[kk][m], bfr[kk][n], acc[m][n], 0, 0, 0);
    __syncthreads();
  }

#pragma unroll
  for (int m = 0; m < 4; ++m) {
    int rbase = mt * BM + wrow + m * 16 + lk * 4;
#pragma unroll
    for (int j2 = 0; j2 < 4; ++j2) {
      int r2 = rbase + j2;
      if (r2 < cnt) {
        int t = idx[off + r2];
        float cf = coef[t];
#pragma unroll
        for (int n = 0; n < 4; ++n) {
          int col = n0 + wcol + n * 16 + lr;
          out[(size_t)t * DD + col] = cf * (acc[m][n][j2] + b2[e * DD + col]);
        }
      }
    }
  }
}

// ---------------- launch ----------------
extern "C" void kernel_launch(void* const* d_in, const int* in_sizes, int n_in,
                              void* d_out, int out_size, void* d_ws, size_t ws_size,
                              hipStream_t stream)
{
  const float* x  = (const float*)d_in[0];
  const float* W1 = (const float*)d_in[1];
  const float* b1 = (const float*)d_in[2];
  const float* W2 = (const float*)d_in[3];
  const float* b2 = (const float*)d_in[4];
  const float* Wg = (const float*)d_in[5];
  const float* bg = (const float*)d_in[6];
  float* out = (float*)d_out;

  char* ws = (char*)d_ws;
  size_t o = 0;
  int* offs   = (int*)(ws + o); o += 64;
  int2* tiles = (int2*)(ws + o); o += MAXT * 8;
  int* bhist  = (int*)(ws + o); o += NBLK * EE * 4;
  int* bbase  = (int*)(ws + o); o += NBLK * EE * 4;
  int* eid    = (int*)(ws + o); o += (size_t)NTOK * 4;
  float* coef = (float*)(ws + o); o += (size_t)NTOK * 4;
  int* idx    = (int*)(ws + o); o += (size_t)NTOK * 4;
  o = (o + 255) & ~(size_t)255;
  __bf16* xbf = (__bf16*)(ws + o); o += (size_t)NTOK * DD * 2;
  __bf16* w1t = (__bf16*)(ws + o); o += (size_t)EE * HH * DD * 2;
  __bf16* w2t = (__bf16*)(ws + o); o += (size_t)EE * DD * HH * 2;
  __bf16* hbuf = (__bf16*)(ws + o); o += (size_t)NTOK * HH * 2;

  k_gating<<<NTOK / 8, 256, 0, stream>>>(x, Wg, bg, eid, coef);
  k_hist<<<NBLK, 256, 0, stream>>>(eid, bhist);
  k_scan<<<1, 64, 0, stream>>>(bhist, offs, bbase, tiles);
  k_scatter<<<NBLK, 256, 0, stream>>>(eid, bbase, idx);
  k_xbf<<<2048, 256, 0, stream>>>(x, xbf);
  k_transpose<<<dim3(HH / 32, DD / 256, EE), 256, 0, stream>>>(W1, w1t, DD, HH);
  k_transpose<<<dim3(DD / 32, HH / 256, EE), 256, 0, stream>>>(W2, w2t, HH, DD);
  k_gemm1<<<dim3(MAXT, HH / BN), 256, 0, stream>>>(xbf, w1t, b1, idx, offs, tiles, hbuf);
  k_gemm2<<<dim3(MAXT, DD / BN), 256, 0, stream>>>(hbuf, w2t, b2, idx, offs, tiles, coef, out);
}

// Round 4
// 876.638 us; speedup vs baseline: 2.0108x; 1.0081x over previous
//
#include <hip/hip_runtime.h>
#include <hip/hip_bf16.h>
#include <math.h>

#define NTOK 32768
#define DD   1024
#define HH   2048
#define EE   8

#define BM 256
#define BN 256
#define BK 64
#define MAXT2 144  // max 256-row tiles: 128 + 7 worst-case, padded
#define NBLK 128   // NTOK / 256

typedef __bf16 bf16x8 __attribute__((ext_vector_type(8)));
typedef __bf16 bf16x4 __attribute__((ext_vector_type(4)));
typedef float  f32x4  __attribute__((ext_vector_type(4)));

__device__ __forceinline__ void gload_lds16(const void* g, void* l) {
  __builtin_amdgcn_global_load_lds((__attribute__((address_space(1))) void*)(g),
                                   (__attribute__((address_space(3))) void*)(l),
                                   16, 0, 0);
}

// ---------------- gating + fused x->bf16 cast ----------------
// f64 accumulation so our argmax matches the "true" routing on near-ties.
__global__ __launch_bounds__(256) void k_gating(
    const float* __restrict__ x, const float* __restrict__ wg,
    const float* __restrict__ bg, int* __restrict__ eid,
    float* __restrict__ coef, __bf16* __restrict__ xbf)
{
  int lane = threadIdx.x & 63;
  int wave = threadIdx.x >> 6;
  int t0 = blockIdx.x * 8 + wave * 2;

  const float* xr0 = x + (size_t)t0 * DD;
  const float* xr1 = x + (size_t)(t0 + 1) * DD;
  double s0[8] = {}, s1[8] = {};
#pragma unroll
  for (int it = 0; it < 4; ++it) {
    int c0 = it * 256 + lane * 4;
    float4 xa = *(const float4*)(xr0 + c0);
    float4 xb = *(const float4*)(xr1 + c0);
    bf16x4 ca, cb;
#pragma unroll
    for (int j = 0; j < 4; ++j) { ca[j] = (__bf16)(&xa.x)[j]; cb[j] = (__bf16)(&xb.x)[j]; }
    *(bf16x4*)(xbf + (size_t)t0 * DD + c0) = ca;
    *(bf16x4*)(xbf + (size_t)(t0 + 1) * DD + c0) = cb;
    const float* w = wg + (size_t)c0 * EE;
#pragma unroll
    for (int j = 0; j < 4; ++j) {
      double fa = (double)(&xa.x)[j];
      double fb = (double)(&xb.x)[j];
#pragma unroll
      for (int e2 = 0; e2 < 8; ++e2) {
        double wv = (double)w[j * EE + e2];
        s0[e2] += fa * wv;
        s1[e2] += fb * wv;
      }
    }
  }

  int sel = lane & 1, sel2 = (lane >> 1) & 1, sel3 = (lane >> 2) & 1;
  int e = (lane & 1) * 4 + (lane & 2) + ((lane >> 2) & 1);
  double bge = (double)bg[e];

#pragma unroll
  for (int tk = 0; tk < 2; ++tk) {
    double* s = tk ? s1 : s0;
    double v4[4];
#pragma unroll
    for (int j = 0; j < 4; ++j) {
      double keep = sel ? s[4 + j] : s[j];
      double send = sel ? s[j] : s[4 + j];
      v4[j] = keep + __shfl_xor(send, 1, 64);
    }
    double v2[2];
#pragma unroll
    for (int j = 0; j < 2; ++j) {
      double keep = sel2 ? v4[2 + j] : v4[j];
      double send = sel2 ? v4[j] : v4[2 + j];
      v2[j] = keep + __shfl_xor(send, 2, 64);
    }
    double keep = sel3 ? v2[1] : v2[0];
    double send = sel3 ? v2[0] : v2[1];
    double tt = keep + __shfl_xor(send, 4, 64);
    tt += __shfl_xor(tt, 8, 64);
    tt += __shfl_xor(tt, 16, 64);
    tt += __shfl_xor(tt, 32, 64);
    double logit = tt + bge;
    double ml = logit; int me = e;
#pragma unroll
    for (int d2 = 1; d2 < 8; d2 <<= 1) {
      double ol = __shfl_xor(ml, d2, 64);
      int oe = __shfl_xor(me, d2, 64);
      if (ol > ml || (ol == ml && oe < me)) { ml = ol; me = oe; }
    }
    double se = exp(logit - ml);
#pragma unroll
    for (int d2 = 1; d2 < 8; d2 <<= 1) se += __shfl_xor(se, d2, 64);
    if (lane == 0) {
      eid[t0 + tk] = me;
      coef[t0 + tk] = (float)(1.0 / se);
    }
  }
}

// ---------------- per-block histogram (LDS atomics only) ----------------
__global__ __launch_bounds__(256) void k_hist(const int* __restrict__ eid,
                                              int* __restrict__ bhist) {
  __shared__ int h[EE];
  if (threadIdx.x < EE) h[threadIdx.x] = 0;
  __syncthreads();
  int t = blockIdx.x * 256 + threadIdx.x;
  atomicAdd(&h[eid[t]], 1);
  __syncthreads();
  if (threadIdx.x < EE) bhist[blockIdx.x * EE + threadIdx.x] = h[threadIdx.x];
}

// ---------------- scan: offs, per-block bases, 256-tile table ----------------
__global__ void k_scan(const int* __restrict__ bhist, int* __restrict__ offs,
                       int* __restrict__ bbase, int2* __restrict__ tiles) {
  __shared__ int counts_s[EE];
  __shared__ int offs_s[EE + 1];
  int lane = threadIdx.x;
  if (lane < EE) {
    int sum = 0;
    for (int b = 0; b < NBLK; ++b) sum += bhist[b * EE + lane];
    counts_s[lane] = sum;
  }
  __syncthreads();
  if (lane == 0) {
    int a = 0;
    for (int e = 0; e < EE; ++e) { offs_s[e] = a; offs[e] = a; a += counts_s[e]; }
    offs_s[EE] = a; offs[EE] = a;
    int nt = 0;
    for (int e = 0; e < EE; ++e)
      for (int mt = 0; mt * BM < counts_s[e]; ++mt) tiles[nt++] = make_int2(e, mt);
    for (; nt < MAXT2; ++nt) tiles[nt] = make_int2(-1, 0);
  }
  __syncthreads();
  if (lane < EE) {
    int run = offs_s[lane];
    for (int b = 0; b < NBLK; ++b) {
      bbase[b * EE + lane] = run;
      run += bhist[b * EE + lane];
    }
  }
}

// ---------------- scatter via LDS cursors into disjoint ranges ----------------
__global__ __launch_bounds__(256) void k_scatter(const int* __restrict__ eid,
                                                 const int* __restrict__ bbase,
                                                 int* __restrict__ idx) {
  __shared__ int cur[EE];
  if (threadIdx.x < EE) cur[threadIdx.x] = bbase[blockIdx.x * EE + threadIdx.x];
  __syncthreads();
  int t = blockIdx.x * 256 + threadIdx.x;
  int e = eid[t];
  int p = atomicAdd(&cur[e], 1);
  idx[p] = t;
}

// ---------------- weight transpose+cast: w[e][R][C] f32 -> wt[e][C][R] bf16 --------
__global__ __launch_bounds__(256) void k_transpose(
    const float* __restrict__ w, __bf16* __restrict__ wt, int R, int C)
{
  __shared__ float tile[32][33];
  int e = blockIdx.z;
  int c0 = blockIdx.x * 32, rb = blockIdx.y * 256;
  const float* we = w + (size_t)e * R * C;
  __bf16* wte = wt + (size_t)e * R * C;
  int tx = threadIdx.x & 31, ty = threadIdx.x >> 5;
  for (int s = 0; s < 8; ++s) {
    int r0 = rb + s * 32;
#pragma unroll
    for (int j = 0; j < 32; j += 8)
      tile[ty + j][tx] = we[(size_t)(r0 + ty + j) * C + (c0 + tx)];
    __syncthreads();
#pragma unroll
    for (int j = 0; j < 32; j += 8)
      wte[(size_t)(c0 + ty + j) * R + (r0 + tx)] = (__bf16)tile[tx][ty + j];
    __syncthreads();
  }
}

// ---------------- GEMM 1: 256x256 tile, 2-phase LDS double-buffer ----------------
__global__ __launch_bounds__(512, 2) void k_gemm1(
    const __bf16* __restrict__ xbf, const __bf16* __restrict__ w1t,
    const float* __restrict__ b1, const int* __restrict__ idx,
    const int* __restrict__ offs, const int2* __restrict__ tiles,
    __bf16* __restrict__ hbuf)
{
  int2 te = tiles[blockIdx.x];
  int e = te.x;
  if (e < 0) return;
  int mt = te.y, nt = blockIdx.y;
  int off = offs[e], cnt = offs[e + 1] - off;
  int n0 = nt * BN;

  __shared__ __align__(16) char smem[131072];  // [A0|A1|B0|B1] x 32KB
  char* sA = smem;
  char* sB = smem + 65536;

  const int tid = threadIdx.x;
  const int lane = tid & 63;
  const int wid = tid >> 6;
  const int wr = wid >> 2, wc = wid & 3;
  const int lr = lane & 15, lk = lane >> 4;

  int tokr[4], srow[4], sch[4];
#pragma unroll
  for (int i = 0; i < 4; ++i) {
    int q = i * 512 + tid;
    int row = q >> 3;
    srow[i] = row;
    sch[i] = (q & 7) ^ (row & 7);
    int rl = mt * BM + row; if (rl >= cnt) rl = cnt - 1;
    tokr[i] = idx[off + rl];
  }
  const char* bsrc = (const char*)(w1t + ((size_t)e * HH + n0) * DD);

  f32x4 acc[8][4] = {};

  // prologue: stage K-tile 0 into buf 0
#pragma unroll
  for (int i = 0; i < 4; ++i)
    gload_lds16((const char*)xbf + ((size_t)tokr[i] * DD) * 2 + sch[i] * 16,
                sA + (i * 512 + tid) * 16);
#pragma unroll
  for (int i = 0; i < 4; ++i)
    gload_lds16(bsrc + (size_t)srow[i] * (DD * 2) + sch[i] * 16,
                sB + (i * 512 + tid) * 16);
  __syncthreads();

  int cur = 0;
  for (int kt = 0; kt < DD / BK; ++kt) {
    if (kt + 1 < DD / BK) {
      int k0 = (kt + 1) * BK;
      char* dA = sA + (cur ^ 1) * 32768;
      char* dB = sB + (cur ^ 1) * 32768;
#pragma unroll
      for (int i = 0; i < 4; ++i)
        gload_lds16((const char*)xbf + ((size_t)tokr[i] * DD + k0) * 2 + sch[i] * 16,
                    dA + (i * 512 + tid) * 16);
#pragma unroll
      for (int i = 0; i < 4; ++i)
        gload_lds16(bsrc + (size_t)srow[i] * (DD * 2) + (size_t)k0 * 2 + sch[i] * 16,
                    dB + (i * 512 + tid) * 16);
    }
    __builtin_amdgcn_sched_barrier(0);
    const char* cAb = sA + cur * 32768;
    const char* cBb = sB + cur * 32768;
#pragma unroll
    for (int kk = 0; kk < 2; ++kk) {
      bf16x8 af[8], bf[4];
#pragma unroll
      for (int m = 0; m < 8; ++m) {
        int row = wr * 128 + m * 16 + lr;
        af[m] = *(const bf16x8*)(cAb + row * 128 + (((kk * 4 + lk) ^ (row & 7)) * 16));
      }
#pragma unroll
      for (int n = 0; n < 4; ++n) {
        int row = wc * 64 + n * 16 + lr;
        bf[n] = *(const bf16x8*)(cBb + row * 128 + (((kk * 4 + lk) ^ (row & 7)) * 16));
      }
      __builtin_amdgcn_s_setprio(1);
#pragma unroll
      for (int m = 0; m < 8; ++m)
#pragma unroll
        for (int n = 0; n < 4; ++n)
          acc[m][n] = __builtin_amdgcn_mfma_f32_16x16x32_bf16(af[m], bf[n], acc[m][n], 0, 0, 0);
      __builtin_amdgcn_s_setprio(0);
    }
    __syncthreads();
    cur ^= 1;
  }

  // epilogue: bias + exact GELU -> bf16 h (compacted rows)
#pragma unroll
  for (int m = 0; m < 8; ++m) {
    int rb = mt * BM + wr * 128 + m * 16 + lk * 4;
#pragma unroll
    for (int n = 0; n < 4; ++n) {
      int col = n0 + wc * 64 + n * 16 + lr;
      float bias = b1[e * HH + col];
#pragma unroll
      for (int j = 0; j < 4; ++j) {
        int r = rb + j;
        if (r < cnt) {
          float vv = acc[m][n][j] + bias;
          float g = 0.5f * vv * (1.0f + erff(vv * 0.70710678118654752f));
          hbuf[(size_t)(off + r) * HH + col] = (__bf16)g;
        }
      }
    }
  }
}

// ---------------- GEMM 2: 256x256 tile, 2-phase LDS double-buffer ----------------
__global__ __launch_bounds__(512, 2) void k_gemm2(
    const __bf16* __restrict__ hbuf, const __bf16* __restrict__ w2t,
    const float* __restrict__ b2, const int* __restrict__ idx,
    const int* __restrict__ offs, const int2* __restrict__ tiles,
    const float* __restrict__ coef, float* __restrict__ out)
{
  int2 te = tiles[blockIdx.x];
  int e = te.x;
  if (e < 0) return;
  int mt = te.y, nt = blockIdx.y;
  int off = offs[e], cnt = offs[e + 1] - off;
  int n0 = nt * BN;

  __shared__ __align__(16) char smem[131072];
  char* sA = smem;
  char* sB = smem + 65536;

  const int tid = threadIdx.x;
  const int lane = tid & 63;
  const int wid = tid >> 6;
  const int wr = wid >> 2, wc = wid & 3;
  const int lr = lane & 15, lk = lane >> 4;

  int arow[4], srow[4], sch[4];
#pragma unroll
  for (int i = 0; i < 4; ++i) {
    int q = i * 512 + tid;
    int row = q >> 3;
    srow[i] = row;
    sch[i] = (q & 7) ^ (row & 7);
    int rl = mt * BM + row; if (rl >= cnt) rl = cnt - 1;
    arow[i] = off + rl;
  }
  const char* bsrc = (const char*)(w2t + ((size_t)e * DD + n0) * HH);

  f32x4 acc[8][4] = {};

#pragma unroll
  for (int i = 0; i < 4; ++i)
    gload_lds16((const char*)hbuf + ((size_t)arow[i] * HH) * 2 + sch[i] * 16,
                sA + (i * 512 + tid) * 16);
#pragma unroll
  for (int i = 0; i < 4; ++i)
    gload_lds16(bsrc + (size_t)srow[i] * (HH * 2) + sch[i] * 16,
                sB + (i * 512 + tid) * 16);
  __syncthreads();

  int cur = 0;
  for (int kt = 0; kt < HH / BK; ++kt) {
    if (kt + 1 < HH / BK) {
      int k0 = (kt + 1) * BK;
      char* dA = sA + (cur ^ 1) * 32768;
      char* dB = sB + (cur ^ 1) * 32768;
#pragma unroll
      for (int i = 0; i < 4; ++i)
        gload_lds16((const char*)hbuf + ((size_t)arow[i] * HH + k0) * 2 + sch[i] * 16,
                    dA + (i * 512 + tid) * 16);
#pragma unroll
      for (int i = 0; i < 4; ++i)
        gload_lds16(bsrc + (size_t)srow[i] * (HH * 2) + (size_t)k0 * 2 + sch[i] * 16,
                    dB + (i * 512 + tid) * 16);
    }
    __builtin_amdgcn_sched_barrier(0);
    const char* cAb = sA + cur * 32768;
    const char* cBb = sB + cur * 32768;
#pragma unroll
    for (int kk = 0; kk < 2; ++kk) {
      bf16x8 af[8], bf[4];
#pragma unroll
      for (int m = 0; m < 8; ++m) {
        int row = wr * 128 + m * 16 + lr;
        af[m] = *(const bf16x8*)(cAb + row * 128 + (((kk * 4 + lk) ^ (row & 7)) * 16));
      }
#pragma unroll
      for (int n = 0; n < 4; ++n) {
        int row = wc * 64 + n * 16 + lr;
        bf[n] = *(const bf16x8*)(cBb + row * 128 + (((kk * 4 + lk) ^ (row & 7)) * 16));
      }
      __builtin_amdgcn_s_setprio(1);
#pragma unroll
      for (int m = 0; m < 8; ++m)
#pragma unroll
        for (int n = 0; n < 4; ++n)
          acc[m][n] = __builtin_amdgcn_mfma_f32_16x16x32_bf16(af[m], bf[n], acc[m][n], 0, 0, 0);
      __builtin_amdgcn_s_setprio(0);
    }
    __syncthreads();
    cur ^= 1;
  }

  // epilogue: scale by coef, add b2, scatter rows to out (f32)
#pragma unroll
  for (int m = 0; m < 8; ++m) {
    int rb = mt * BM + wr * 128 + m * 16 + lk * 4;
#pragma unroll
    for (int j = 0; j < 4; ++j) {
      int r = rb + j;
      if (r < cnt) {
        int t = idx[off + r];
        float cf = coef[t];
#pragma unroll
        for (int n = 0; n < 4; ++n) {
          int col = n0 + wc * 64 + n * 16 + lr;
          out[(size_t)t * DD + col] = cf * (acc[m][n][j] + b2[e * DD + col]);
        }
      }
    }
  }
}

// ---------------- launch ----------------
extern "C" void kernel_launch(void* const* d_in, const int* in_sizes, int n_in,
                              void* d_out, int out_size, void* d_ws, size_t ws_size,
                              hipStream_t stream)
{
  const float* x  = (const float*)d_in[0];
  const float* W1 = (const float*)d_in[1];
  const float* b1 = (const float*)d_in[2];
  const float* W2 = (const float*)d_in[3];
  const float* b2 = (const float*)d_in[4];
  const float* Wg = (const float*)d_in[5];
  const float* bg = (const float*)d_in[6];
  float* out = (float*)d_out;

  char* ws = (char*)d_ws;
  size_t o = 0;
  int* offs   = (int*)(ws + o); o += 64;
  int2* tiles = (int2*)(ws + o); o += MAXT2 * 8;
  int* bhist  = (int*)(ws + o); o += NBLK * EE * 4;
  int* bbase  = (int*)(ws + o); o += NBLK * EE * 4;
  int* eid    = (int*)(ws + o); o += (size_t)NTOK * 4;
  float* coef = (float*)(ws + o); o += (size_t)NTOK * 4;
  int* idx    = (int*)(ws + o); o += (size_t)NTOK * 4;
  o = (o + 255) & ~(size_t)255;
  __bf16* xbf = (__bf16*)(ws + o); o += (size_t)NTOK * DD * 2;
  __bf16* w1t = (__bf16*)(ws + o); o += (size_t)EE * HH * DD * 2;
  __bf16* w2t = (__bf16*)(ws + o); o += (size_t)EE * DD * HH * 2;
  __bf16* hbuf = (__bf16*)(ws + o); o += (size_t)NTOK * HH * 2;

  k_gating<<<NTOK / 8, 256, 0, stream>>>(x, Wg, bg, eid, coef, xbf);
  k_hist<<<NBLK, 256, 0, stream>>>(eid, bhist);
  k_scan<<<1, 64, 0, stream>>>(bhist, offs, bbase, tiles);
  k_scatter<<<NBLK, 256, 0, stream>>>(eid, bbase, idx);
  k_transpose<<<dim3(HH / 32, DD / 256, EE), 256, 0, stream>>>(W1, w1t, DD, HH);
  k_transpose<<<dim3(DD / 32, HH / 256, EE), 256, 0, stream>>>(W2, w2t, HH, DD);
  k_gemm1<<<dim3(MAXT2, HH / BN), 512, 0, stream>>>(xbf, w1t, b1, idx, offs, tiles, hbuf);
  k_gemm2<<<dim3(MAXT2, DD / BN), 512, 0, stream>>>(hbuf, w2t, b2, idx, offs, tiles, coef, out);
}